// Round 8
// baseline (91.464 us; speedup 1.0000x reference)
//
#include <hip/hip_runtime.h>

// RankingLoss via bucket-ordering, TWO dispatches (R7 post-mortem: inter-dispatch
// overhead ~8-10us dominates; kernel work is ~12us total).
//   K1 sort_k (16 blocks): R7's verified fused hist+scatter (whole-array packed
//      hist -> wave scan -> own-range exact scatter) + zero acc slots / done.
//   K2 rank_k (512 blocks): R6's verified paired-group brute rank (full region
//      3 VALU/pair + exact compare/ballot band) + FENCELESS fused finish:
//      per-block atomicAdd(double) into 8 spread slots, s_waitcnt vmcnt(0),
//      atomicAdd(done); last block (old==NB-1) reads slots atomically -> out.
//      Atomics-only visibility (coherent point), NO __threadfence (R2 lesson:
//      per-thread fences cost ~60us in L2 writebacks across XCDs).

constexpr float MARGIN = 0.1f;
constexpr int NBINS = 256;    // t-bins (== T)
constexpr int SB    = 16;     // sort blocks; per-block range = n/SB = 1024
constexpr int RT    = 16;     // rows per group
constexpr int T     = 256;    // threads per block
constexpr int NSLOT = 8;      // accumulator slots (64B apart: contention spread)

__device__ __forceinline__ int bin_of(float t) {
    int b = (int)(t * (float)NBINS);   // monotone; equal t -> equal bin
    b = b < 0 ? 0 : (b > NBINS - 1 ? NBINS - 1 : b);
    return b;
}

// K1: fused hist + scatter (verified in R7). lhp packs (total | before-block).
__global__ __launch_bounds__(T) void sort_k(const float* __restrict__ pred,
                                            const float* __restrict__ target,
                                            float* __restrict__ ts,
                                            float* __restrict__ ps,
                                            int* __restrict__ Bg,
                                            double* __restrict__ acc,
                                            int* __restrict__ done, int n) {
    __shared__ int lhp[NBINS];    // low16: total; high16: count in [0, base)
    __shared__ int sbase[NBINS];  // global bin start + prev-blocks count
    __shared__ int lcnt[NBINS];
    __shared__ int wsum[T / 64];

    const int tid = (int)threadIdx.x;
    const int k   = (int)blockIdx.x;
    lhp[tid] = 0; lcnt[tid] = 0;
    __syncthreads();

    const int per    = n / SB;        // 1024
    const int base   = k * per;
    const int basef4 = base >> 2;
    const int nf4    = n >> 2;        // 4096
    const float4* __restrict__ t4 = (const float4*)target;
    const float4* __restrict__ p4 = (const float4*)pred;

    for (int f = tid; f < nf4; f += T) {          // whole array: 16 float4/thread
        const float4 tv = t4[f];
        const int inc = (f < basef4) ? 0x10001 : 1;
        atomicAdd(&lhp[bin_of(tv.x)], inc);
        atomicAdd(&lhp[bin_of(tv.y)], inc);
        atomicAdd(&lhp[bin_of(tv.z)], inc);
        atomicAdd(&lhp[bin_of(tv.w)], inc);
    }
    __syncthreads();

    const int tot = lhp[tid] & 0xFFFF;
    const int prv = lhp[tid] >> 16;

    int incl = tot;                                // verified wave-scan
    #pragma unroll
    for (int off = 1; off < 64; off <<= 1) {
        int v = __shfl_up(incl, off, 64);
        if ((tid & 63) >= off) incl += v;
    }
    if ((tid & 63) == 63) wsum[tid >> 6] = incl;
    __syncthreads();
    int woff = 0;
    for (int w = 0; w < (tid >> 6); ++w) woff += wsum[w];
    const int bb = woff + incl - tot;
    sbase[tid] = bb + prv;
    if (k == 0) {                                  // block 0: prv==0, bb is global
        Bg[tid] = bb;
        if (tid == 0) { Bg[NBINS] = n; done[0] = 0; }
        if (tid < NSLOT) acc[tid * 8] = 0.0;       // 8 slots, 64B apart
    }
    __syncthreads();

    const float4 tv = t4[basef4 + tid];            // own range: 1 float4/thread
    const float4 pvv = p4[basef4 + tid];
    { const int b = bin_of(tv.x); const int r = atomicAdd(&lcnt[b], 1);
      const int pos = sbase[b] + r; ts[pos] = tv.x; ps[pos] = pvv.x; }
    { const int b = bin_of(tv.y); const int r = atomicAdd(&lcnt[b], 1);
      const int pos = sbase[b] + r; ts[pos] = tv.y; ps[pos] = pvv.y; }
    { const int b = bin_of(tv.z); const int r = atomicAdd(&lcnt[b], 1);
      const int pos = sbase[b] + r; ts[pos] = tv.z; ps[pos] = pvv.z; }
    { const int b = bin_of(tv.w); const int r = atomicAdd(&lcnt[b], 1);
      const int pos = sbase[b] + r; ts[pos] = tv.w; ps[pos] = pvv.w; }
}

// K2: paired-group brute rank (verified in R6) + fenceless fused finish.
__global__ __launch_bounds__(T) void rank_k(const float* __restrict__ ts,
                                            const float* __restrict__ ps,
                                            const int* __restrict__ B,
                                            double* __restrict__ acc,
                                            int* __restrict__ done,
                                            float* __restrict__ out, int n) {
    const int NG = n / RT;                      // 1024 row-groups
    const int bid = (int)blockIdx.x;            // 512 blocks

    const float4* __restrict__ p4 = (const float4*)ps;
    const float4* __restrict__ t4 = (const float4*)ts;

    const int tid  = (int)threadIdx.x;
    const int lane = tid & 63;
    const int wv   = tid >> 6;
    __shared__ float ls[T / 64][RT];
    __shared__ unsigned int lc[T / 64][RT];

    double blockacc = 0.0;                      // valid on tid 0 only

    for (int gg = 0; gg < 2; ++gg) {
        const int g = (gg == 0) ? bid : (NG - 1 - bid);
        const int q = g * RT;

        float ti[RT], ci[RT];
        #pragma unroll
        for (int r = 0; r < RT; ++r) {
            ti[r] = ts[q + r];
            ci[r] = MARGIN - ps[q + r];
        }

        const int Blo = B[bin_of(ti[0])];            // j < Blo: all rows qualify
        const int Bhi = B[bin_of(ti[RT - 1]) + 1];   // j >= Bhi: none qualify
        const int M0 = Blo & ~3;
        int M1 = (Bhi + 3) & ~3;
        if (M1 > n) M1 = n;

        float sum[RT];
        #pragma unroll
        for (int r = 0; r < RT; ++r) sum[r] = 0.f;

        // Full region: unconditional hinge, 3 VALU/pair.
        const int f4 = M0 >> 2;
        for (int j = tid; j < f4; j += T) {
            const float4 pj = p4[j];
            #pragma unroll
            for (int r = 0; r < RT; ++r) {
                sum[r] += fmaxf(0.f, ci[r] + pj.x);
                sum[r] += fmaxf(0.f, ci[r] + pj.y);
                sum[r] += fmaxf(0.f, ci[r] + pj.z);
                sum[r] += fmaxf(0.f, ci[r] + pj.w);
            }
        }

        // Boundary band: exact strict compares + ballot counts.
        unsigned int cnt[RT];
        #pragma unroll
        for (int r = 0; r < RT; ++r) cnt[r] = 0u;

        const int m4lo = M0 >> 2, m4hi = M1 >> 2;
        const int iters = (m4hi - m4lo + T - 1) / T;   // block-uniform
        for (int it = 0; it < iters; ++it) {
            const int j = m4lo + it * T + tid;
            const bool inb = j < m4hi;
            const int jc = inb ? j : m4lo;
            const float4 tj = t4[jc];
            const float4 pj = p4[jc];
            #pragma unroll
            for (int r = 0; r < RT; ++r) {
                { bool m = inb && (tj.x < ti[r]); float h = fmaxf(0.f, ci[r] + pj.x);
                  sum[r] += m ? h : 0.f; cnt[r] += (unsigned)__popcll(__ballot(m)); }
                { bool m = inb && (tj.y < ti[r]); float h = fmaxf(0.f, ci[r] + pj.y);
                  sum[r] += m ? h : 0.f; cnt[r] += (unsigned)__popcll(__ballot(m)); }
                { bool m = inb && (tj.z < ti[r]); float h = fmaxf(0.f, ci[r] + pj.z);
                  sum[r] += m ? h : 0.f; cnt[r] += (unsigned)__popcll(__ballot(m)); }
                { bool m = inb && (tj.w < ti[r]); float h = fmaxf(0.f, ci[r] + pj.w);
                  sum[r] += m ? h : 0.f; cnt[r] += (unsigned)__popcll(__ballot(m)); }
            }
        }

        // Block-level reduction (verified).
        #pragma unroll
        for (int r = 0; r < RT; ++r) {
            float sv = sum[r];
            #pragma unroll
            for (int off = 32; off > 0; off >>= 1) sv += __shfl_down(sv, off, 64);
            if (lane == 0) { ls[wv][r] = sv; lc[wv][r] = cnt[r]; }
        }
        __syncthreads();

        float val = 0.f;
        if (tid < RT) {
            float sv = 0.f;
            unsigned int c = (unsigned int)M0;       // full region counts every row
            #pragma unroll
            for (int w = 0; w < T / 64; ++w) { sv += ls[w][tid]; c += lc[w][tid]; }
            val = (c > 0u) ? sv / (float)c : 0.f;
        }
        if (tid < 64) {
            #pragma unroll
            for (int off = 8; off > 0; off >>= 1) val += __shfl_down(val, off, 64);
        }
        if (tid == 0) blockacc += (double)val;
        __syncthreads();                             // ls/lc reused next group
    }

    // Fenceless fused finish (atomics-only visibility; NO __threadfence).
    if (tid == 0) {
        atomicAdd(&acc[(bid & (NSLOT - 1)) * 8], blockacc);
        // Ensure the acc atomic has completed at the coherent point before
        // signalling done. "memory" clobber stops reordering of memory ops.
        asm volatile("s_waitcnt vmcnt(0)" ::: "memory");
        const int old = atomicAdd(done, 1);
        if (old == (int)gridDim.x - 1) {             // all acc-adds completed
            double s = 0.0;
            #pragma unroll
            for (int i = 0; i < NSLOT; ++i) s += atomicAdd(&acc[i * 8], 0.0);
            out[0] = (float)(s / (double)n);
        }
    }
}

extern "C" void kernel_launch(void* const* d_in, const int* in_sizes, int n_in,
                              void* d_out, int out_size, void* d_ws, size_t ws_size,
                              hipStream_t stream) {
    const float* pred   = (const float*)d_in[0];
    const float* target = (const float*)d_in[1];
    const int n = in_sizes[0];                 // 16384
    const int NG = n / RT;                     // 1024
    const int NB = NG / 2;                     // 512 rank blocks (paired groups)

    char* w = (char*)d_ws;
    size_t o = 0;
    auto alloc = [&](size_t bytes) {
        void* p = w + o;
        o = (o + bytes + 255) & ~(size_t)255;
        return p;
    };
    float*  ts   = (float*)alloc((size_t)n * 4);
    float*  ps   = (float*)alloc((size_t)n * 4);
    int*    B    = (int*)alloc((size_t)(NBINS + 1) * 4);
    double* acc  = (double*)alloc((size_t)NSLOT * 8 * 8);
    int*    done = (int*)alloc(16);

    sort_k<<<SB, T, 0, stream>>>(pred, target, ts, ps, B, acc, done, n);
    rank_k<<<NB, T, 0, stream>>>(ts, ps, B, acc, done, (float*)d_out, n);
}

// Round 9
// 83.708 us; speedup vs baseline: 1.0926x; 1.0926x over previous
//
#include <hip/hip_runtime.h>

// RankingLoss via bucket-ordering. REVERT to the verified best (R5, 85.26us).
// Session evidence (R0-R8): total is dominated by fixed harness machinery
// (268MB poison-fill = 39.5us @85% HBM peak + reset dispatch train); our chain
// is ~12us and total is insensitive to further work reduction (R7 closed-form:
// -40% work, +3.6us) or dispatch fusion (R8 2-dispatch: +6.2us). Structure
// below is the reproducible optimum: split hist/scatter @ NBINS=256, brute
// prefix rank, separate deterministic final. NO device fences, no contended
// global atomics (R2: per-thread __threadfence cost ~60us in L2 writebacks).
//   K1 hist_k   (16 blocks): per-block private histograms (LDS), H[blk][bin].
//   K2 scatter_k(16 blocks): redundant in-LDS scan of H -> exact sorted position
//                            = binbase + prev-blocks-count + LDS local rank.
//   K3 rank_k (1024 blocks): sorted-prefix hinge sums. Full region: 3 VALU/pair.
//                            Boundary band: exact compare + ballot.
//   K4 final_k  (1 block):   deterministic fixed-order double sum of partials.

constexpr float MARGIN = 0.1f;
constexpr int NBINS = 256;    // == T: one bin per thread in the scan
constexpr int HB    = 16;     // hist/scatter blocks; per-block range = n/HB = 1024
constexpr int RT    = 16;     // rows per rank block
constexpr int T     = 256;    // threads per block

__device__ __forceinline__ int bin_of(float t) {
    int b = (int)(t * (float)NBINS);   // monotone; equal t -> equal bin
    b = b < 0 ? 0 : (b > NBINS - 1 ? NBINS - 1 : b);
    return b;
}

// K1: per-block private histograms, H[blk*NBINS + bin]. No global zeroing needed.
__global__ __launch_bounds__(T) void hist_k(const float* __restrict__ target,
                                            int* __restrict__ H, int n) {
    __shared__ int lh[NBINS];
    const int tid = (int)threadIdx.x;
    lh[tid] = 0;                                   // NBINS == T
    __syncthreads();
    const int per = n / HB;                        // 1024 elems == 256 float4s
    const float4 tv = ((const float4*)(target + (int)blockIdx.x * per))[tid];
    atomicAdd(&lh[bin_of(tv.x)], 1);
    atomicAdd(&lh[bin_of(tv.y)], 1);
    atomicAdd(&lh[bin_of(tv.z)], 1);
    atomicAdd(&lh[bin_of(tv.w)], 1);
    __syncthreads();
    H[(int)blockIdx.x * NBINS + tid] = lh[tid];    // coalesced
}

// K2: redundant in-block scan of H + exact scatter (LDS atomics only).
__global__ __launch_bounds__(T) void scatter_k(const float* __restrict__ pred,
                                               const float* __restrict__ target,
                                               const int* __restrict__ H,
                                               float* __restrict__ ts,
                                               float* __restrict__ ps,
                                               int* __restrict__ Bg, int n) {
    __shared__ int bbase[NBINS];   // exclusive bin prefix (global start of bin)
    __shared__ int prevk[NBINS];   // count of this bin in element-blocks < k
    __shared__ int lcnt[NBINS];    // local (within-block) rank counters
    __shared__ int wsum[T / 64];

    const int tid = (int)threadIdx.x;
    const int k   = (int)blockIdx.x;

    // one bin per thread; H[q][bin=tid] is lane-coalesced for each q
    int tot = 0, prv = 0;
    #pragma unroll
    for (int q = 0; q < HB; ++q) {
        const int h = H[q * NBINS + tid];
        tot += h;
        prv += (q < k) ? h : 0;
    }
    lcnt[tid] = 0;

    // exclusive prefix across the block (1 value/thread)
    int incl = tot;
    #pragma unroll
    for (int off = 1; off < 64; off <<= 1) {
        int v = __shfl_up(incl, off, 64);
        if ((tid & 63) >= off) incl += v;
    }
    if ((tid & 63) == 63) wsum[tid >> 6] = incl;
    __syncthreads();
    int woff = 0;
    for (int w = 0; w < (tid >> 6); ++w) woff += wsum[w];
    bbase[tid] = woff + incl - tot;
    prevk[tid] = prv;
    __syncthreads();

    // scatter this block's element range (same ranges as hist_k!)
    const int per = n / HB;                        // 1024 -> 1 float4/thread
    const float4 tv = ((const float4*)(target + k * per))[tid];
    const float4 pv = ((const float4*)(pred   + k * per))[tid];
    {
        const int b = bin_of(tv.x); const int r = atomicAdd(&lcnt[b], 1);
        const int pos = bbase[b] + prevk[b] + r; ts[pos] = tv.x; ps[pos] = pv.x;
    }
    {
        const int b = bin_of(tv.y); const int r = atomicAdd(&lcnt[b], 1);
        const int pos = bbase[b] + prevk[b] + r; ts[pos] = tv.y; ps[pos] = pv.y;
    }
    {
        const int b = bin_of(tv.z); const int r = atomicAdd(&lcnt[b], 1);
        const int pos = bbase[b] + prevk[b] + r; ts[pos] = tv.z; ps[pos] = pv.z;
    }
    {
        const int b = bin_of(tv.w); const int r = atomicAdd(&lcnt[b], 1);
        const int pos = bbase[b] + prevk[b] + r; ts[pos] = tv.w; ps[pos] = pv.w;
    }

    if (k == 0) {
        Bg[tid] = bbase[tid];
        if (tid == 0) Bg[NBINS] = n;
    }
}

// K3: sorted-prefix hinge sums. Plain partials store, no fences.
__global__ __launch_bounds__(T) void rank_k(const float* __restrict__ ts,
                                            const float* __restrict__ ps,
                                            const int* __restrict__ B,
                                            float* __restrict__ partials, int n) {
    const int nblk = (int)gridDim.x;
    const int g = nblk - 1 - (int)blockIdx.x;   // heavy-first
    const int q = g * RT;

    float ti[RT], ci[RT];
    #pragma unroll
    for (int r = 0; r < RT; ++r) {
        ti[r] = ts[q + r];
        ci[r] = MARGIN - ps[q + r];
    }

    const int Blo = B[bin_of(ti[0])];            // j < Blo: qualifies for all rows
    const int Bhi = B[bin_of(ti[RT - 1]) + 1];   // j >= Bhi: qualifies for none
    const int M0 = Blo & ~3;
    int M1 = (Bhi + 3) & ~3;
    if (M1 > n) M1 = n;

    float sum[RT];
    #pragma unroll
    for (int r = 0; r < RT; ++r) sum[r] = 0.f;

    const float4* __restrict__ p4 = (const float4*)ps;
    const float4* __restrict__ t4 = (const float4*)ts;

    // Full region: unconditional hinge, 3 VALU/pair.
    const int f4 = M0 >> 2;
    for (int j = (int)threadIdx.x; j < f4; j += T) {
        const float4 pj = p4[j];
        #pragma unroll
        for (int r = 0; r < RT; ++r) {
            sum[r] += fmaxf(0.f, ci[r] + pj.x);
            sum[r] += fmaxf(0.f, ci[r] + pj.y);
            sum[r] += fmaxf(0.f, ci[r] + pj.z);
            sum[r] += fmaxf(0.f, ci[r] + pj.w);
        }
    }

    // Boundary band: exact strict compares + ballot counts.
    unsigned int cnt[RT];
    #pragma unroll
    for (int r = 0; r < RT; ++r) cnt[r] = 0u;

    const int m4lo = M0 >> 2, m4hi = M1 >> 2;
    const int iters = (m4hi - m4lo + T - 1) / T;   // block-uniform
    for (int it = 0; it < iters; ++it) {
        const int j = m4lo + it * T + (int)threadIdx.x;
        const bool inb = j < m4hi;
        const int jc = inb ? j : m4lo;
        const float4 tj = t4[jc];
        const float4 pj = p4[jc];
        #pragma unroll
        for (int r = 0; r < RT; ++r) {
            { bool m = inb && (tj.x < ti[r]); float h = fmaxf(0.f, ci[r] + pj.x);
              sum[r] += m ? h : 0.f; cnt[r] += (unsigned)__popcll(__ballot(m)); }
            { bool m = inb && (tj.y < ti[r]); float h = fmaxf(0.f, ci[r] + pj.y);
              sum[r] += m ? h : 0.f; cnt[r] += (unsigned)__popcll(__ballot(m)); }
            { bool m = inb && (tj.z < ti[r]); float h = fmaxf(0.f, ci[r] + pj.z);
              sum[r] += m ? h : 0.f; cnt[r] += (unsigned)__popcll(__ballot(m)); }
            { bool m = inb && (tj.w < ti[r]); float h = fmaxf(0.f, ci[r] + pj.w);
              sum[r] += m ? h : 0.f; cnt[r] += (unsigned)__popcll(__ballot(m)); }
        }
    }

    // Block-level reduction.
    __shared__ float ls[T / 64][RT];
    __shared__ unsigned int lc[T / 64][RT];
    const int lane = (int)threadIdx.x & 63;
    const int wv   = (int)threadIdx.x >> 6;
    #pragma unroll
    for (int r = 0; r < RT; ++r) {
        float sv = sum[r];
        #pragma unroll
        for (int off = 32; off > 0; off >>= 1) sv += __shfl_down(sv, off, 64);
        if (lane == 0) { ls[wv][r] = sv; lc[wv][r] = cnt[r]; }
    }
    __syncthreads();

    float val = 0.f;
    if ((int)threadIdx.x < RT) {
        float sv = 0.f;
        unsigned int c = (unsigned int)M0;       // full region counts for every row
        #pragma unroll
        for (int w = 0; w < T / 64; ++w) { sv += ls[w][threadIdx.x]; c += lc[w][threadIdx.x]; }
        val = (c > 0u) ? sv / (float)c : 0.f;
    }
    if ((int)threadIdx.x < 64) {
        #pragma unroll
        for (int off = 8; off > 0; off >>= 1) val += __shfl_down(val, off, 64);
    }
    if (threadIdx.x == 0) partials[blockIdx.x] = val;
}

// K4: deterministic fixed-order reduction of partials (1024 floats, 1 float4/thread).
__global__ __launch_bounds__(T) void final_k(const float* __restrict__ partials,
                                             float* __restrict__ out, int n, int nblk) {
    const int n4 = nblk >> 2;
    double s = 0.0;
    for (int i = (int)threadIdx.x; i < n4; i += T) {
        float4 v = ((const float4*)partials)[i];
        s += (double)v.x + (double)v.y + (double)v.z + (double)v.w;
    }
    #pragma unroll
    for (int off = 32; off > 0; off >>= 1) s += __shfl_down(s, off, 64);
    __shared__ double sd[T / 64];
    const int lane = (int)threadIdx.x & 63, wv = (int)threadIdx.x >> 6;
    if (lane == 0) sd[wv] = s;
    __syncthreads();
    if (threadIdx.x == 0) {
        double t = 0.0;
        #pragma unroll
        for (int w = 0; w < T / 64; ++w) t += sd[w];
        out[0] = (float)(t / (double)n);
    }
}

extern "C" void kernel_launch(void* const* d_in, const int* in_sizes, int n_in,
                              void* d_out, int out_size, void* d_ws, size_t ws_size,
                              hipStream_t stream) {
    const float* pred   = (const float*)d_in[0];
    const float* target = (const float*)d_in[1];
    const int n = in_sizes[0];                 // 16384
    const int nblk = n / RT;                   // 1024

    char* w = (char*)d_ws;
    size_t o = 0;
    auto alloc = [&](size_t bytes) {
        void* p = w + o;
        o = (o + bytes + 255) & ~(size_t)255;
        return p;
    };
    float* ts       = (float*)alloc((size_t)n * 4);
    float* ps       = (float*)alloc((size_t)n * 4);
    int*   H        = (int*)alloc((size_t)NBINS * HB * 4);
    int*   B        = (int*)alloc((size_t)(NBINS + 1) * 4);
    float* partials = (float*)alloc((size_t)nblk * 4);

    hist_k<<<HB, T, 0, stream>>>(target, H, n);
    scatter_k<<<HB, T, 0, stream>>>(pred, target, H, ts, ps, B, n);
    rank_k<<<nblk, T, 0, stream>>>(ts, ps, B, partials, n);
    final_k<<<1, T, 0, stream>>>(partials, (float*)d_out, n, nblk);
}